// Round 3
// baseline (492.759 us; speedup 1.0000x reference)
//
#include <hip/hip_runtime.h>
#include <hip/hip_bf16.h>
#include <stdint.h>
#include <stddef.h>

typedef __bf16 bf16_t;
typedef __attribute__((ext_vector_type(8))) __bf16 bf16x8;
typedef __attribute__((ext_vector_type(4))) __bf16 bf16x4;
typedef __attribute__((ext_vector_type(4))) float f32x4;
typedef __attribute__((ext_vector_type(4))) int i32x4;

#define M_DIM 32768
#define N_DIM 4096
#define K_DIM 1024
#define NT (K_DIM / 32)  // 32 k-tiles of BK=32

static __device__ __forceinline__ void gload16(const void* g, void* s) {
  // async global->LDS, 16B per lane; LDS dest is wave-uniform base + lane*16
  __builtin_amdgcn_global_load_lds(
      (const __attribute__((address_space(1))) void*)g,
      (__attribute__((address_space(3))) void*)s,
      16, 0, 0);
}

// ---------------- x: fp32 [M][K] -> bf16 [M][K] ----------------
__global__ void cvt_x_kernel(const float* __restrict__ x, bf16_t* __restrict__ xb) {
  const long n8 = (long)M_DIM * K_DIM / 8;
  long i = (long)blockIdx.x * blockDim.x + threadIdx.x;
  const long stride = (long)gridDim.x * blockDim.x;
  for (; i < n8; i += stride) {
    const float4* p = (const float4*)(x + i * 8);
    float4 v0 = p[0];
    float4 v1 = p[1];
    bf16x8 o;
    o[0] = (__bf16)v0.x; o[1] = (__bf16)v0.y; o[2] = (__bf16)v0.z; o[3] = (__bf16)v0.w;
    o[4] = (__bf16)v1.x; o[5] = (__bf16)v1.y; o[6] = (__bf16)v1.z; o[7] = (__bf16)v1.w;
    *(bf16x8*)(xb + i * 8) = o;
  }
}

// ---------------- w: int32 [K][N] -> bf16 Wt [N][K] (exact) ----------------
__global__ void cvt_w_kernel(const int* __restrict__ qw, bf16_t* __restrict__ wt) {
  __shared__ bf16_t t[64][72];
  const int bk = blockIdx.x & 15;   // K/64 = 16
  const int bn = blockIdx.x >> 4;   // N/64 = 64
  const int k0 = bk * 64, n0 = bn * 64;
  const int tid = threadIdx.x;
  {
    const int kl = tid >> 2;
    const int nc = (tid & 3) * 16;
    const int* src = qw + (long)(k0 + kl) * N_DIM + n0 + nc;
#pragma unroll
    for (int c = 0; c < 4; ++c) {
      i32x4 v = *(const i32x4*)(src + c * 4);
#pragma unroll
      for (int j = 0; j < 4; ++j)
        t[nc + c * 4 + j][kl] = (bf16_t)(float)v[j];
    }
  }
  __syncthreads();
  {
    const int nl = tid >> 2;
    const int kc = (tid & 3) * 16;
    bf16_t* dst = wt + (long)(n0 + nl) * K_DIM + k0 + kc;
#pragma unroll
    for (int j = 0; j < 16; ++j) dst[j] = t[nl][kc + j];
  }
}

// ---------------- GEMM 256x256, BK=32, 8 waves, 4-deep LDS rotation ------
// C = (A @ Bt^T) * scale + bias ; A bf16 [M][K], Bt bf16 [N][K]
// Counted-vmcnt pipeline: stage tile t+3 at iter t; wait vmcnt(8) per iter
// (2 tiles = 8 loads stay in flight across barriers; never drains to 0).
__global__ __launch_bounds__(512, 1) void gemm256_kernel(
    const bf16_t* __restrict__ A, const bf16_t* __restrict__ Bt,
    const float* __restrict__ scale_p, const float* __restrict__ bias,
    float* __restrict__ C) {
  // 4 rotating buffers x (A 16KB + B 16KB) = 128 KB
  __shared__ __align__(16) bf16_t lA[4][256 * 32];
  __shared__ __align__(16) bf16_t lB[4][256 * 32];

  // XCD-bijective swizzle (nwg = 2048 % 8 == 0): each XCD walks tm within tn
  const int nwg = gridDim.x;
  int wg = blockIdx.x;
  wg = (wg & 7) * (nwg >> 3) + (wg >> 3);
  const int tm = wg & 127;  // M/256 = 128
  const int tn = wg >> 7;   // N/256 = 16

  const int tid = threadIdx.x;
  const int wave = tid >> 6;
  const int lane = tid & 63;
  const int lr = lane & 15;
  const int lg = lane >> 4;
  const int wm = wave >> 2;  // 0..1  -> rows wm*128..+128
  const int wn = wave & 3;   // 0..3  -> cols wn*64..+64

  const long aRow0 = (long)tm * 256;
  const long bRow0 = (long)tn * 256;
  // staging source: issue i covers rows [i*128, i*128+128), thread t -> row tid/4, 8-elem chunk tid%4
  const bf16_t* aSrc = A + (aRow0 + (tid >> 2)) * K_DIM + (tid & 3) * 8;
  const bf16_t* bSrc = Bt + (bRow0 + (tid >> 2)) * K_DIM + (tid & 3) * 8;
  // wave-uniform LDS staging bases (each wave's 64 lanes fill 1KB = 16 rows)
  char* ldsA0 = (char*)&lA[0][0] + wave * 1024;
  char* ldsB0 = (char*)&lB[0][0] + wave * 1024;

  // per-thread fragment read offsets (bytes); [256][32] rows are 64B so a
  // wave's 64 lanes of one frag-read cover a contiguous 1KB block: conflict-free
  const int aoff = ((wm * 128 + lr) * 32 + lg * 8) * 2;
  const int boff = ((wn * 64 + lr) * 32 + lg * 8) * 2;

  f32x4 acc[8][4] = {};

#define STAGE(t)                                                    \
  do {                                                              \
    const int _b = (t) & 3;                                         \
    const bf16_t* _as = aSrc + (t) * 32;                            \
    const bf16_t* _bs = bSrc + (t) * 32;                            \
    gload16(_as, ldsA0 + _b * 16384);                               \
    gload16(_as + 128 * K_DIM, ldsA0 + _b * 16384 + 8192);          \
    gload16(_bs, ldsB0 + _b * 16384);                               \
    gload16(_bs + 128 * K_DIM, ldsB0 + _b * 16384 + 8192);          \
  } while (0)

#define COMPUTE(t)                                                            \
  do {                                                                        \
    const char* _pa = (const char*)&lA[0][0] + ((t) & 3) * 16384 + aoff;      \
    const char* _pb = (const char*)&lB[0][0] + ((t) & 3) * 16384 + boff;      \
    bf16x8 _a[8], _bf[4];                                                     \
    _Pragma("unroll") for (int m = 0; m < 8; ++m)                             \
        _a[m] = *(const bf16x8*)(_pa + m * 1024);                             \
    _Pragma("unroll") for (int n = 0; n < 4; ++n)                             \
        _bf[n] = *(const bf16x8*)(_pb + n * 1024);                            \
    __builtin_amdgcn_s_setprio(1);                                            \
    _Pragma("unroll") for (int m = 0; m < 8; ++m)                             \
      _Pragma("unroll") for (int n = 0; n < 4; ++n)                           \
          acc[m][n] = __builtin_amdgcn_mfma_f32_16x16x32_bf16(                \
              _a[m], _bf[n], acc[m][n], 0, 0, 0);                             \
    __builtin_amdgcn_s_setprio(0);                                            \
  } while (0)

  // counted wait + raw barrier; sched_barrier pins MFMA/ds_read on their side
#define TILE_SYNC(Nimm)                                      \
  do {                                                       \
    asm volatile("s_waitcnt vmcnt(" #Nimm ")" ::: "memory"); \
    __builtin_amdgcn_s_barrier();                            \
    __builtin_amdgcn_sched_barrier(0);                       \
  } while (0)

  // prologue: 3 tiles in flight
  STAGE(0);
  STAGE(1);
  STAGE(2);
  TILE_SYNC(8);  // tile 0 landed (8 newer loads remain in flight)

#pragma unroll 1
  for (int t = 0; t < NT - 3; ++t) {  // t = 0..28
    STAGE(t + 3);                     // rewrites buffer read at iter t-1 (safe: post-barrier)
    COMPUTE(t);
    TILE_SYNC(8);                     // tile t+1 landed; tiles t+2,t+3 in flight
  }
  COMPUTE(NT - 3);
  TILE_SYNC(4);   // tile NT-2 landed
  COMPUTE(NT - 2);
  TILE_SYNC(0);   // tile NT-1 landed
  COMPUTE(NT - 1);

#undef STAGE
#undef COMPUTE
#undef TILE_SYNC

  // epilogue: C/D layout col = lane&15, row = (lane>>4)*4 + reg
  const float s = *scale_p;
  const int col_base = (tn << 8) + wn * 64;
  const int row_base = (tm << 8) + wm * 128 + lg * 4;
#pragma unroll
  for (int n = 0; n < 4; ++n) {
    const int col = col_base + n * 16 + lr;
    const float bv = bias[col];
#pragma unroll
    for (int m = 0; m < 8; ++m) {
      float* cp = C + (long)(row_base + m * 16) * N_DIM + col;
#pragma unroll
      for (int j = 0; j < 4; ++j)
        cp[(long)j * N_DIM] = acc[m][n][j] * s + bv;
    }
  }
}

// ---------------- fallback (ws too small): round-2 128^2 kernel ----------
__global__ __launch_bounds__(256, 2) void gemm_fb_kernel(
    const float* __restrict__ Af, const bf16_t* __restrict__ Bt,
    const float* __restrict__ scale_p, const float* __restrict__ bias,
    float* __restrict__ C) {
  __shared__ bf16_t lA[128][64];
  __shared__ bf16_t lB[128][64];
  const int nwg = gridDim.x;
  int wg = blockIdx.x;
  wg = (wg & 7) * (nwg >> 3) + (wg >> 3);
  const int tm = wg & 255;
  const int tn = wg >> 8;
  const int tid = threadIdx.x;
  const int wave = tid >> 6;
  const int lane = tid & 63;
  const int lr = lane & 15;
  const int lg = lane >> 4;
  const int wm = wave >> 1;
  const int wn = wave & 1;
  const long aRow0 = (long)tm * 128;
  const long bRow0 = (long)tn * 128;
  const bf16_t* bSrc = Bt + (bRow0 + (tid >> 3)) * K_DIM + (tid & 7) * 8;
  char* ldsB = (char*)&lB[0][0] + wave * 1024;
  f32x4 acc[4][4] = {};
  for (int k0 = 0; k0 < K_DIM; k0 += 64) {
    __syncthreads();
#pragma unroll
    for (int j = 0; j < 8; ++j) {
      const int e = j * 1024 + tid * 4;
      const int row = e >> 6;
      const int col = e & 63;
      float4 v = *(const float4*)(Af + (aRow0 + row) * K_DIM + k0 + col);
      bf16x4 o;
      o[0] = (__bf16)v.x; o[1] = (__bf16)v.y; o[2] = (__bf16)v.z; o[3] = (__bf16)v.w;
      *(bf16x4*)((char*)&lA[0][0] + (size_t)e * 2) = o;
    }
#pragma unroll
    for (int i = 0; i < 4; ++i)
      gload16(bSrc + (long)i * 32 * K_DIM + k0, ldsB + i * 4096);
    __syncthreads();
#pragma unroll
    for (int kk = 0; kk < 2; ++kk) {
      bf16x8 af[4], bg[4];
#pragma unroll
      for (int m = 0; m < 4; ++m)
        af[m] = *(const bf16x8*)&lA[wm * 64 + m * 16 + lr][kk * 32 + lg * 8];
#pragma unroll
      for (int n = 0; n < 4; ++n)
        bg[n] = *(const bf16x8*)&lB[wn * 64 + n * 16 + lr][kk * 32 + lg * 8];
#pragma unroll
      for (int m = 0; m < 4; ++m)
#pragma unroll
        for (int n = 0; n < 4; ++n)
          acc[m][n] = __builtin_amdgcn_mfma_f32_16x16x32_bf16(af[m], bg[n], acc[m][n], 0, 0, 0);
    }
  }
  const float s = *scale_p;
  const int col0 = (tn << 7) + wn * 64;
  const int row0 = (tm << 7) + wm * 64 + lg * 4;
#pragma unroll
  for (int n = 0; n < 4; ++n) {
    const int col = col0 + n * 16 + lr;
    const float bv = bias[col];
#pragma unroll
    for (int m = 0; m < 4; ++m) {
      float* cp = C + (long)(row0 + m * 16) * N_DIM + col;
#pragma unroll
      for (int j = 0; j < 4; ++j)
        cp[(long)j * N_DIM] = acc[m][n][j] * s + bv;
    }
  }
}

extern "C" void kernel_launch(void* const* d_in, const int* in_sizes, int n_in,
                              void* d_out, int out_size, void* d_ws, size_t ws_size,
                              hipStream_t stream) {
  const float* x = (const float*)d_in[0];
  const int* qw = (const int*)d_in[1];  // harness pushes ints as int32
  const float* scale = (const float*)d_in[2];
  const float* bias = (const float*)d_in[3];
  float* out = (float*)d_out;

  const size_t wt_bytes = (size_t)N_DIM * K_DIM * 2;  // 8 MB
  const size_t xb_bytes = (size_t)M_DIM * K_DIM * 2;  // 64 MB
  bf16_t* wt = (bf16_t*)d_ws;
  bf16_t* xb = (bf16_t*)((char*)d_ws + wt_bytes);
  const bool apre = ws_size >= wt_bytes + xb_bytes;

  cvt_w_kernel<<<dim3((K_DIM / 64) * (N_DIM / 64)), dim3(256), 0, stream>>>(qw, wt);

  if (apre) {
    cvt_x_kernel<<<dim3(2048), dim3(256), 0, stream>>>(x, xb);
    gemm256_kernel<<<dim3((M_DIM / 256) * (N_DIM / 256)), dim3(512), 0, stream>>>(
        xb, wt, scale, bias, out);
  } else {
    gemm_fb_kernel<<<dim3((M_DIM / 128) * (N_DIM / 128)), dim3(256), 0, stream>>>(
        x, wt, scale, bias, out);
  }
}

// Round 4
// 383.294 us; speedup vs baseline: 1.2856x; 1.2856x over previous
//
#include <hip/hip_runtime.h>
#include <hip/hip_bf16.h>
#include <stdint.h>
#include <stddef.h>

typedef __bf16 bf16_t;
typedef __attribute__((ext_vector_type(8))) __bf16 bf16x8;
typedef __attribute__((ext_vector_type(4))) __bf16 bf16x4;
typedef __attribute__((ext_vector_type(4))) float f32x4;
typedef __attribute__((ext_vector_type(4))) int i32x4;

#define M_DIM 32768
#define N_DIM 4096
#define K_DIM 1024
#define NT 16  // K / 64

static __device__ __forceinline__ void gload16(const void* g, void* s) {
  // async global->LDS, 16B per lane; LDS dest is wave-uniform base + lane*16
  __builtin_amdgcn_global_load_lds(
      (const __attribute__((address_space(1))) void*)g,
      (__attribute__((address_space(3))) void*)s,
      16, 0, 0);
}

// ---------------- x: fp32 [M][K] -> bf16 [M][K] ----------------
__global__ void cvt_x_kernel(const float* __restrict__ x, bf16_t* __restrict__ xb) {
  const long n8 = (long)M_DIM * K_DIM / 8;
  long i = (long)blockIdx.x * blockDim.x + threadIdx.x;
  const long stride = (long)gridDim.x * blockDim.x;
  for (; i < n8; i += stride) {
    const float4* p = (const float4*)(x + i * 8);
    float4 v0 = p[0];
    float4 v1 = p[1];
    bf16x8 o;
    o[0] = (__bf16)v0.x; o[1] = (__bf16)v0.y; o[2] = (__bf16)v0.z; o[3] = (__bf16)v0.w;
    o[4] = (__bf16)v1.x; o[5] = (__bf16)v1.y; o[6] = (__bf16)v1.z; o[7] = (__bf16)v1.w;
    *(bf16x8*)(xb + i * 8) = o;
  }
}

// ---------------- w: int32 [K][N] -> bf16 Wt [N][K] (exact) ----------------
__global__ void cvt_w_kernel(const int* __restrict__ qw, bf16_t* __restrict__ wt) {
  __shared__ bf16_t t[64][72];
  const int bk = blockIdx.x & 15;   // K/64 = 16
  const int bn = blockIdx.x >> 4;   // N/64 = 64
  const int k0 = bk * 64, n0 = bn * 64;
  const int tid = threadIdx.x;
  {
    const int kl = tid >> 2;
    const int nc = (tid & 3) * 16;
    const int* src = qw + (long)(k0 + kl) * N_DIM + n0 + nc;
#pragma unroll
    for (int c = 0; c < 4; ++c) {
      i32x4 v = *(const i32x4*)(src + c * 4);
#pragma unroll
      for (int j = 0; j < 4; ++j)
        t[nc + c * 4 + j][kl] = (bf16_t)(float)v[j];
    }
  }
  __syncthreads();
  {
    const int nl = tid >> 2;
    const int kc = (tid & 3) * 16;
    bf16_t* dst = wt + (long)(n0 + nl) * K_DIM + k0 + kc;
#pragma unroll
    for (int j = 0; j < 16; ++j) dst[j] = t[nl][kc + j];
  }
}

// ---------------- GEMM 256x256, BK=64, 8 waves, 4-phase counted-vmcnt ----
// C = (A @ Bt^T) * scale + bias ; A bf16 [M][K], Bt bf16 [N][K]
// LDS 128KB: buf b: A at b*65536 (32KB, [256 slots][64 cols], swizzled),
//                   B at b*65536+32768 (32KB).
// Swizzle: 16B-chunk ^= (slot&7); staged via pre-swizzled GLOBAL source
// (gload_lds dest linear), read with the same XOR -> b128 reads at bank floor.
// A-halves row-interleaved so all waves' m0-3 frags are in half 0:
//   half h, issue 0 -> global rows h*64+[0,64); issue 1 -> 128+h*64+[0,64).
// Per K-tile: PH1{vmcnt(2),bar; read B-all+A-lo; stage A-lo'; 16 MFMA}
//             PH2{stage B-lo'; 16 MFMA}
//             PH3{vmcnt(4),bar; read A-hi; stage B-hi'; 16 MFMA}
//             PH4{stage A-hi'; 16 MFMA}
__global__ __launch_bounds__(512, 1) void gemm256_kernel(
    const bf16_t* __restrict__ A, const bf16_t* __restrict__ Bt,
    const float* __restrict__ scale_p, const float* __restrict__ bias,
    float* __restrict__ C) {
  __shared__ __align__(16) char lds[131072];

  // XCD-bijective swizzle (nwg = 2048 % 8 == 0)
  const int nwg = gridDim.x;
  int wg = blockIdx.x;
  wg = (wg & 7) * (nwg >> 3) + (wg >> 3);
  const int tm = wg & 127;  // M/256 = 128
  const int tn = wg >> 7;   // N/256 = 16

  const int tid = threadIdx.x;
  const int wave = tid >> 6;
  const int lane = tid & 63;
  const int lr = lane & 15;
  const int lg = lane >> 4;
  const int wm = wave >> 2;  // 0..1
  const int wn = wave & 3;   // 0..3

  const long aRow0 = (long)tm * 256;
  const long bRow0 = (long)tn * 256;

  // staging: thread covers slot = (stripe) + wave*8 + lane/8; source col chunk
  // pre-swizzled by slot&7 == lane>>3
  const int srow = wave * 8 + (lane >> 3);
  const int scol = ((lane & 7) ^ (lane >> 3)) * 8;
  const bf16_t* aS = A + (aRow0 + srow) * K_DIM + scol;
  const bf16_t* bS = Bt + (bRow0 + srow) * K_DIM + scol;
  char* sBase = lds + wave * 1024;  // wave-uniform LDS staging base

#define STG_A(b, h, t)                                              \
  do {                                                              \
    gload16(aS + (long)((h) * 64) * K_DIM + (t) * 64,               \
            sBase + (b) * 65536 + (h) * 16384);                     \
    gload16(aS + (long)(128 + (h) * 64) * K_DIM + (t) * 64,         \
            sBase + (b) * 65536 + (h) * 16384 + 8192);              \
  } while (0)
#define STG_B(b, h, t)                                              \
  do {                                                              \
    gload16(bS + (long)((h) * 128) * K_DIM + (t) * 64,              \
            sBase + (b) * 65536 + 32768 + (h) * 16384);             \
    gload16(bS + (long)((h) * 128 + 64) * K_DIM + (t) * 64,         \
            sBase + (b) * 65536 + 32768 + (h) * 16384 + 8192);      \
  } while (0)

  // frag-read bases; slot&7 == lr&7 for every frag (verified arithmetic)
  const int aRd = (wm * 64 + lr) * 128;          // + (m>>2)*16384 + (m&3)*2048 + ck
  const int bRd = 32768 + (wn * 64 + lr) * 128;  // + n*2048 + ck
  const int ck0 = ((0 + lg) ^ (lr & 7)) << 4;
  const int ck1 = ((4 + lg) ^ (lr & 7)) << 4;

#define LDA(m, kk) \
  (*(const bf16x8*)(lds + bb + aRd + ((m) >> 2) * 16384 + ((m) & 3) * 2048 + ((kk) ? ck1 : ck0)))
#define LDB(n, kk) \
  (*(const bf16x8*)(lds + bb + bRd + (n) * 2048 + ((kk) ? ck1 : ck0)))

#define SYNC(Nimm)                                           \
  do {                                                       \
    asm volatile("s_waitcnt vmcnt(" #Nimm ")" ::: "memory"); \
    __builtin_amdgcn_s_barrier();                            \
    __builtin_amdgcn_sched_barrier(0);                       \
  } while (0)

  f32x4 acc[8][4] = {};
  bf16x8 bfr[4][2], afr[4][2];

#define MFMA_Q(mbase, nbase)                                                   \
  do {                                                                         \
    __builtin_amdgcn_s_setprio(1);                                             \
    _Pragma("unroll") for (int m = 0; m < 4; ++m)                              \
    _Pragma("unroll") for (int n = 0; n < 2; ++n)                              \
    _Pragma("unroll") for (int kk = 0; kk < 2; ++kk)                           \
      acc[(mbase) + m][(nbase) + n] =                                          \
          __builtin_amdgcn_mfma_f32_16x16x32_bf16(                             \
              afr[m][kk], bfr[(nbase) + n][kk], acc[(mbase) + m][(nbase) + n], \
              0, 0, 0);                                                        \
    __builtin_amdgcn_s_setprio(0);                                             \
  } while (0)

  // prologue: tile 0 halves in order A-lo, B-lo, B-hi, A-hi (8 loads)
  STG_A(0, 0, 0);
  STG_B(0, 0, 0);
  STG_B(0, 1, 0);
  STG_A(0, 1, 0);

#pragma unroll 1
  for (int t = 0; t < NT - 1; ++t) {
    const int b = t & 1;
    const int nb = b ^ 1;
    const int bb = b * 65536;
    // PH1: A-lo,B-lo,B-hi of tile t landed (keep A-hi + nothing else in flight)
    SYNC(2);
#pragma unroll
    for (int n = 0; n < 4; ++n) { bfr[n][0] = LDB(n, 0); bfr[n][1] = LDB(n, 1); }
#pragma unroll
    for (int m = 0; m < 4; ++m) { afr[m][0] = LDA(m, 0); afr[m][1] = LDA(m, 1); }
    STG_A(nb, 0, t + 1);
    MFMA_Q(0, 0);
    // PH2
    STG_B(nb, 0, t + 1);
    MFMA_Q(0, 2);
    // PH3: A-hi(t) landed (outstanding: A-lo',B-lo' stay in flight)
    SYNC(4);
#pragma unroll
    for (int m = 0; m < 4; ++m) { afr[m][0] = LDA(m + 4, 0); afr[m][1] = LDA(m + 4, 1); }
    STG_B(nb, 1, t + 1);
    MFMA_Q(4, 0);
    // PH4
    STG_A(nb, 1, t + 1);
    MFMA_Q(4, 2);
  }
  {  // t = NT-1 (odd -> buf 1), no staging; vmcnt(0) allowed in epilogue
    const int bb = 65536;
    SYNC(2);
#pragma unroll
    for (int n = 0; n < 4; ++n) { bfr[n][0] = LDB(n, 0); bfr[n][1] = LDB(n, 1); }
#pragma unroll
    for (int m = 0; m < 4; ++m) { afr[m][0] = LDA(m, 0); afr[m][1] = LDA(m, 1); }
    MFMA_Q(0, 0);
    MFMA_Q(0, 2);
    SYNC(0);
#pragma unroll
    for (int m = 0; m < 4; ++m) { afr[m][0] = LDA(m + 4, 0); afr[m][1] = LDA(m + 4, 1); }
    MFMA_Q(4, 0);
    MFMA_Q(4, 2);
  }

#undef STG_A
#undef STG_B
#undef LDA
#undef LDB
#undef SYNC
#undef MFMA_Q

  // epilogue: C/D layout col = lane&15, row = (lane>>4)*4 + reg
  const float s = *scale_p;
  const int col_base = (tn << 8) + wn * 64;
  const int row_base = (tm << 8) + wm * 128 + lg * 4;
#pragma unroll
  for (int n = 0; n < 4; ++n) {
    const int col = col_base + n * 16 + lr;
    const float bv = bias[col];
#pragma unroll
    for (int m = 0; m < 8; ++m) {
      float* cp = C + (long)(row_base + m * 16) * N_DIM + col;
#pragma unroll
      for (int j = 0; j < 4; ++j)
        cp[(long)j * N_DIM] = acc[m][n][j] * s + bv;
    }
  }
}

// ---------------- fallback (ws too small): reg-staged 128^2 kernel --------
__global__ __launch_bounds__(256, 2) void gemm_fb_kernel(
    const float* __restrict__ Af, const bf16_t* __restrict__ Bt,
    const float* __restrict__ scale_p, const float* __restrict__ bias,
    float* __restrict__ C) {
  __shared__ bf16_t lA[128][64];
  __shared__ bf16_t lB[128][64];
  const int nwg = gridDim.x;
  int wg = blockIdx.x;
  wg = (wg & 7) * (nwg >> 3) + (wg >> 3);
  const int tm = wg & 255;
  const int tn = wg >> 8;
  const int tid = threadIdx.x;
  const int wave = tid >> 6;
  const int lane = tid & 63;
  const int lr = lane & 15;
  const int lg = lane >> 4;
  const int wm = wave >> 1;
  const int wn = wave & 1;
  const long aRow0 = (long)tm * 128;
  const long bRow0 = (long)tn * 128;
  const bf16_t* bSrc = Bt + (bRow0 + (tid >> 3)) * K_DIM + (tid & 7) * 8;
  char* ldsB = (char*)&lB[0][0] + wave * 1024;
  f32x4 acc[4][4] = {};
  for (int k0 = 0; k0 < K_DIM; k0 += 64) {
    __syncthreads();
#pragma unroll
    for (int j = 0; j < 8; ++j) {
      const int e = j * 1024 + tid * 4;
      const int row = e >> 6;
      const int col = e & 63;
      float4 v = *(const float4*)(Af + (aRow0 + row) * K_DIM + k0 + col);
      bf16x4 o;
      o[0] = (__bf16)v.x; o[1] = (__bf16)v.y; o[2] = (__bf16)v.z; o[3] = (__bf16)v.w;
      *(bf16x4*)((char*)&lA[0][0] + (size_t)e * 2) = o;
    }
#pragma unroll
    for (int i = 0; i < 4; ++i)
      gload16(bSrc + (long)i * 32 * K_DIM + k0, ldsB + i * 4096);
    __syncthreads();
#pragma unroll
    for (int kk = 0; kk < 2; ++kk) {
      bf16x8 af[4], bg[4];
#pragma unroll
      for (int m = 0; m < 4; ++m)
        af[m] = *(const bf16x8*)&lA[wm * 64 + m * 16 + lr][kk * 32 + lg * 8];
#pragma unroll
      for (int n = 0; n < 4; ++n)
        bg[n] = *(const bf16x8*)&lB[wn * 64 + n * 16 + lr][kk * 32 + lg * 8];
#pragma unroll
      for (int m = 0; m < 4; ++m)
#pragma unroll
        for (int n = 0; n < 4; ++n)
          acc[m][n] = __builtin_amdgcn_mfma_f32_16x16x32_bf16(af[m], bg[n], acc[m][n], 0, 0, 0);
    }
  }
  const float s = *scale_p;
  const int col0 = (tn << 7) + wn * 64;
  const int row0 = (tm << 7) + wm * 64 + lg * 4;
#pragma unroll
  for (int n = 0; n < 4; ++n) {
    const int col = col0 + n * 16 + lr;
    const float bv = bias[col];
#pragma unroll
    for (int m = 0; m < 4; ++m) {
      float* cp = C + (long)(row0 + m * 16) * N_DIM + col;
#pragma unroll
      for (int j = 0; j < 4; ++j)
        cp[(long)j * N_DIM] = acc[m][n][j] * s + bv;
    }
  }
}

extern "C" void kernel_launch(void* const* d_in, const int* in_sizes, int n_in,
                              void* d_out, int out_size, void* d_ws, size_t ws_size,
                              hipStream_t stream) {
  const float* x = (const float*)d_in[0];
  const int* qw = (const int*)d_in[1];  // harness pushes ints as int32
  const float* scale = (const float*)d_in[2];
  const float* bias = (const float*)d_in[3];
  float* out = (float*)d_out;

  const size_t wt_bytes = (size_t)N_DIM * K_DIM * 2;  // 8 MB
  const size_t xb_bytes = (size_t)M_DIM * K_DIM * 2;  // 64 MB
  bf16_t* wt = (bf16_t*)d_ws;
  bf16_t* xb = (bf16_t*)((char*)d_ws + wt_bytes);
  const bool apre = ws_size >= wt_bytes + xb_bytes;

  cvt_w_kernel<<<dim3((K_DIM / 64) * (N_DIM / 64)), dim3(256), 0, stream>>>(qw, wt);

  if (apre) {
    cvt_x_kernel<<<dim3(2048), dim3(256), 0, stream>>>(x, xb);
    gemm256_kernel<<<dim3((M_DIM / 256) * (N_DIM / 256)), dim3(512), 0, stream>>>(
        xb, wt, scale, bias, out);
  } else {
    gemm_fb_kernel<<<dim3((M_DIM / 128) * (N_DIM / 128)), dim3(256), 0, stream>>>(
        x, wt, scale, bias, out);
  }
}

// Round 5
// 342.130 us; speedup vs baseline: 1.4403x; 1.1203x over previous
//
#include <hip/hip_runtime.h>
#include <hip/hip_bf16.h>
#include <stdint.h>
#include <stddef.h>

typedef __bf16 bf16_t;
typedef __attribute__((ext_vector_type(8))) __bf16 bf16x8;
typedef __attribute__((ext_vector_type(4))) __bf16 bf16x4;
typedef __attribute__((ext_vector_type(4))) float f32x4;
typedef __attribute__((ext_vector_type(4))) int i32x4;

#define M_DIM 32768
#define N_DIM 4096
#define K_DIM 1024
#define NT 16  // K / 64

static __device__ __forceinline__ void gload16(const void* g, void* s) {
  // async global->LDS, 16B per lane; LDS dest is wave-uniform base + lane*16
  __builtin_amdgcn_global_load_lds(
      (const __attribute__((address_space(1))) void*)g,
      (__attribute__((address_space(3))) void*)s,
      16, 0, 0);
}

// ---------------- x: fp32 [M][K] -> bf16 [M][K] ----------------
__global__ void cvt_x_kernel(const float* __restrict__ x, bf16_t* __restrict__ xb) {
  const long n8 = (long)M_DIM * K_DIM / 8;
  long i = (long)blockIdx.x * blockDim.x + threadIdx.x;
  const long stride = (long)gridDim.x * blockDim.x;
  for (; i < n8; i += stride) {
    const float4* p = (const float4*)(x + i * 8);
    float4 v0 = p[0];
    float4 v1 = p[1];
    bf16x8 o;
    o[0] = (__bf16)v0.x; o[1] = (__bf16)v0.y; o[2] = (__bf16)v0.z; o[3] = (__bf16)v0.w;
    o[4] = (__bf16)v1.x; o[5] = (__bf16)v1.y; o[6] = (__bf16)v1.z; o[7] = (__bf16)v1.w;
    *(bf16x8*)(xb + i * 8) = o;
  }
}

// ---------------- w: int32 [K][N] -> bf16 Wt [N][K] (exact) ----------------
__global__ void cvt_w_kernel(const int* __restrict__ qw, bf16_t* __restrict__ wt) {
  __shared__ bf16_t t[64][72];
  const int bk = blockIdx.x & 15;   // K/64 = 16
  const int bn = blockIdx.x >> 4;   // N/64 = 64
  const int k0 = bk * 64, n0 = bn * 64;
  const int tid = threadIdx.x;
  {
    const int kl = tid >> 2;
    const int nc = (tid & 3) * 16;
    const int* src = qw + (long)(k0 + kl) * N_DIM + n0 + nc;
#pragma unroll
    for (int c = 0; c < 4; ++c) {
      i32x4 v = *(const i32x4*)(src + c * 4);
#pragma unroll
      for (int j = 0; j < 4; ++j)
        t[nc + c * 4 + j][kl] = (bf16_t)(float)v[j];
    }
  }
  __syncthreads();
  {
    const int nl = tid >> 2;
    const int kc = (tid & 3) * 16;
    bf16_t* dst = wt + (long)(n0 + nl) * K_DIM + k0 + kc;
#pragma unroll
    for (int j = 0; j < 16; ++j) dst[j] = t[nl][kc + j];
  }
}

// ---------------- GEMM 256x256, BK=64, 8 waves, 4-phase counted-vmcnt ----
// C = (A @ Bt^T) * scale + bias ; A bf16 [M][K], Bt bf16 [N][K]
// LDS 128KB: buf b: A at b*65536 (32KB), B at b*65536+32768 (32KB).
// Swizzle: 16B-chunk ^= (slot&7); staged via pre-swizzled GLOBAL source
// (gload_lds dest linear), read with the same XOR -> bank-conflict-free
// (verified: SQ_LDS_BANK_CONFLICT == 0 in round 4).
// Locality (round 5): XCD x permanently owns tn panels {2x, 2x+1} (B slab
// 1MB hot in its L2 for the whole kernel); all XCDs sweep the same 16-tm
// A-stripe (8MB) concurrently, so A is fetched from HBM once into LLC.
__global__ __launch_bounds__(512, 1) void gemm256_kernel(
    const bf16_t* __restrict__ A, const bf16_t* __restrict__ Bt,
    const float* __restrict__ scale_p, const float* __restrict__ bias,
    float* __restrict__ C) {
  __shared__ __align__(16) char lds[131072];

  // ownership mapping (bijective; nwg = 2048 fixed)
  const int xcd = blockIdx.x & 7;   // dispatch round-robins XCDs
  const int slot = blockIdx.x >> 3; // 0..255 per XCD
  const int sweep = slot >> 5;      // 0..7 : which 16-tm A stripe
  const int u = slot & 31;
  const int tn = (xcd << 1) | (u & 1);       // 2 fixed panels per XCD
  const int tm = (sweep << 4) | (u >> 1);    // 0..127

  const int tid = threadIdx.x;
  const int wave = tid >> 6;
  const int lane = tid & 63;
  const int lr = lane & 15;
  const int lg = lane >> 4;
  const int wm = wave >> 2;  // 0..1
  const int wn = wave & 3;   // 0..3

  const long aRow0 = (long)tm * 256;
  const long bRow0 = (long)tn * 256;

  // staging: thread covers slot = wave*8 + lane/8; source col chunk
  // pre-swizzled by slot&7 == lane>>3
  const int srow = wave * 8 + (lane >> 3);
  const int scol = ((lane & 7) ^ (lane >> 3)) * 8;
  const bf16_t* aS = A + (aRow0 + srow) * K_DIM + scol;
  const bf16_t* bS = Bt + (bRow0 + srow) * K_DIM + scol;
  char* sBase = lds + wave * 1024;  // wave-uniform LDS staging base

#define STG_A(b, h, t)                                              \
  do {                                                              \
    gload16(aS + (long)((h) * 64) * K_DIM + (t) * 64,               \
            sBase + (b) * 65536 + (h) * 16384);                     \
    gload16(aS + (long)(128 + (h) * 64) * K_DIM + (t) * 64,         \
            sBase + (b) * 65536 + (h) * 16384 + 8192);              \
  } while (0)
#define STG_B(b, h, t)                                              \
  do {                                                              \
    gload16(bS + (long)((h) * 128) * K_DIM + (t) * 64,              \
            sBase + (b) * 65536 + 32768 + (h) * 16384);             \
    gload16(bS + (long)((h) * 128 + 64) * K_DIM + (t) * 64,         \
            sBase + (b) * 65536 + 32768 + (h) * 16384 + 8192);      \
  } while (0)

  // frag-read bases; slot&7 == lr&7 for every frag
  const int aRd = (wm * 64 + lr) * 128;          // + (m>>2)*16384 + (m&3)*2048 + ck
  const int bRd = 32768 + (wn * 64 + lr) * 128;  // + n*2048 + ck
  const int ck0 = ((0 + lg) ^ (lr & 7)) << 4;
  const int ck1 = ((4 + lg) ^ (lr & 7)) << 4;

#define LDA(m, kk) \
  (*(const bf16x8*)(lds + bb + aRd + ((m) >> 2) * 16384 + ((m) & 3) * 2048 + ((kk) ? ck1 : ck0)))
#define LDB(n, kk) \
  (*(const bf16x8*)(lds + bb + bRd + (n) * 2048 + ((kk) ? ck1 : ck0)))

#define SYNC(Nimm)                                           \
  do {                                                       \
    asm volatile("s_waitcnt vmcnt(" #Nimm ")" ::: "memory"); \
    __builtin_amdgcn_s_barrier();                            \
    __builtin_amdgcn_sched_barrier(0);                       \
  } while (0)

  f32x4 acc[8][4] = {};
  bf16x8 bfr[4][2], afr[4][2];

#define MFMA_Q(mbase, nbase)                                                   \
  do {                                                                         \
    __builtin_amdgcn_s_setprio(1);                                             \
    _Pragma("unroll") for (int m = 0; m < 4; ++m)                              \
    _Pragma("unroll") for (int n = 0; n < 2; ++n)                              \
    _Pragma("unroll") for (int kk = 0; kk < 2; ++kk)                           \
      acc[(mbase) + m][(nbase) + n] =                                          \
          __builtin_amdgcn_mfma_f32_16x16x32_bf16(                             \
              afr[m][kk], bfr[(nbase) + n][kk], acc[(mbase) + m][(nbase) + n], \
              0, 0, 0);                                                        \
    __builtin_amdgcn_s_setprio(0);                                             \
  } while (0)

  // prologue: tile 0 halves in order A-lo, B-lo, B-hi, A-hi (8 loads)
  STG_A(0, 0, 0);
  STG_B(0, 0, 0);
  STG_B(0, 1, 0);
  STG_A(0, 1, 0);

#pragma unroll 1
  for (int t = 0; t < NT - 1; ++t) {
    const int b = t & 1;
    const int nb = b ^ 1;
    const int bb = b * 65536;
    // PH1: A-lo,B-lo,B-hi of tile t landed (A-hi still in flight)
    SYNC(2);
#pragma unroll
    for (int n = 0; n < 4; ++n) { bfr[n][0] = LDB(n, 0); bfr[n][1] = LDB(n, 1); }
#pragma unroll
    for (int m = 0; m < 4; ++m) { afr[m][0] = LDA(m, 0); afr[m][1] = LDA(m, 1); }
    STG_A(nb, 0, t + 1);
    MFMA_Q(0, 0);
    // PH2
    STG_B(nb, 0, t + 1);
    MFMA_Q(0, 2);
    // PH3: A-hi(t) landed (A-lo',B-lo' stay in flight)
    SYNC(4);
#pragma unroll
    for (int m = 0; m < 4; ++m) { afr[m][0] = LDA(m + 4, 0); afr[m][1] = LDA(m + 4, 1); }
    STG_B(nb, 1, t + 1);
    MFMA_Q(4, 0);
    // PH4
    STG_A(nb, 1, t + 1);
    MFMA_Q(4, 2);
  }
  {  // t = NT-1 (odd -> buf 1), no staging
    const int bb = 65536;
    SYNC(2);
#pragma unroll
    for (int n = 0; n < 4; ++n) { bfr[n][0] = LDB(n, 0); bfr[n][1] = LDB(n, 1); }
#pragma unroll
    for (int m = 0; m < 4; ++m) { afr[m][0] = LDA(m, 0); afr[m][1] = LDA(m, 1); }
    MFMA_Q(0, 0);
    MFMA_Q(0, 2);
    SYNC(0);
#pragma unroll
    for (int m = 0; m < 4; ++m) { afr[m][0] = LDA(m + 4, 0); afr[m][1] = LDA(m + 4, 1); }
    MFMA_Q(4, 0);
    MFMA_Q(4, 2);
  }

#undef STG_A
#undef STG_B
#undef LDA
#undef LDB
#undef SYNC
#undef MFMA_Q

  // epilogue: C/D layout col = lane&15, row = (lane>>4)*4 + reg
  // nontemporal stores: keep the 512MB C-stream from evicting A out of LLC
  const float s = *scale_p;
  const int col_base = (tn << 8) + wn * 64;
  const int row_base = (tm << 8) + wm * 128 + lg * 4;
#pragma unroll
  for (int n = 0; n < 4; ++n) {
    const int col = col_base + n * 16 + lr;
    const float bv = bias[col];
#pragma unroll
    for (int m = 0; m < 8; ++m) {
      float* cp = C + (long)(row_base + m * 16) * N_DIM + col;
#pragma unroll
      for (int j = 0; j < 4; ++j)
        __builtin_nontemporal_store(acc[m][n][j] * s + bv, cp + (long)j * N_DIM);
    }
  }
}

// ---------------- fallback (ws too small): reg-staged 128^2 kernel --------
__global__ __launch_bounds__(256, 2) void gemm_fb_kernel(
    const float* __restrict__ Af, const bf16_t* __restrict__ Bt,
    const float* __restrict__ scale_p, const float* __restrict__ bias,
    float* __restrict__ C) {
  __shared__ bf16_t lA[128][64];
  __shared__ bf16_t lB[128][64];
  const int nwg = gridDim.x;
  int wg = blockIdx.x;
  wg = (wg & 7) * (nwg >> 3) + (wg >> 3);
  const int tm = wg & 255;
  const int tn = wg >> 8;
  const int tid = threadIdx.x;
  const int wave = tid >> 6;
  const int lane = tid & 63;
  const int lr = lane & 15;
  const int lg = lane >> 4;
  const int wm = wave >> 1;
  const int wn = wave & 1;
  const long aRow0 = (long)tm * 128;
  const long bRow0 = (long)tn * 128;
  const bf16_t* bSrc = Bt + (bRow0 + (tid >> 3)) * K_DIM + (tid & 7) * 8;
  char* ldsB = (char*)&lB[0][0] + wave * 1024;
  f32x4 acc[4][4] = {};
  for (int k0 = 0; k0 < K_DIM; k0 += 64) {
    __syncthreads();
#pragma unroll
    for (int j = 0; j < 8; ++j) {
      const int e = j * 1024 + tid * 4;
      const int row = e >> 6;
      const int col = e & 63;
      float4 v = *(const float4*)(Af + (aRow0 + row) * K_DIM + k0 + col);
      bf16x4 o;
      o[0] = (__bf16)v.x; o[1] = (__bf16)v.y; o[2] = (__bf16)v.z; o[3] = (__bf16)v.w;
      *(bf16x4*)((char*)&lA[0][0] + (size_t)e * 2) = o;
    }
#pragma unroll
    for (int i = 0; i < 4; ++i)
      gload16(bSrc + (long)i * 32 * K_DIM + k0, ldsB + i * 4096);
    __syncthreads();
#pragma unroll
    for (int kk = 0; kk < 2; ++kk) {
      bf16x8 af[4], bg[4];
#pragma unroll
      for (int m = 0; m < 4; ++m)
        af[m] = *(const bf16x8*)&lA[wm * 64 + m * 16 + lr][kk * 32 + lg * 8];
#pragma unroll
      for (int n = 0; n < 4; ++n)
        bg[n] = *(const bf16x8*)&lB[wn * 64 + n * 16 + lr][kk * 32 + lg * 8];
#pragma unroll
      for (int m = 0; m < 4; ++m)
#pragma unroll
        for (int n = 0; n < 4; ++n)
          acc[m][n] = __builtin_amdgcn_mfma_f32_16x16x32_bf16(af[m], bg[n], acc[m][n], 0, 0, 0);
    }
  }
  const float s = *scale_p;
  const int col0 = (tn << 7) + wn * 64;
  const int row0 = (tm << 7) + wm * 64 + lg * 4;
#pragma unroll
  for (int n = 0; n < 4; ++n) {
    const int col = col0 + n * 16 + lr;
    const float bv = bias[col];
#pragma unroll
    for (int m = 0; m < 4; ++m) {
      float* cp = C + (long)(row0 + m * 16) * N_DIM + col;
#pragma unroll
      for (int j = 0; j < 4; ++j)
        cp[(long)j * N_DIM] = acc[m][n][j] * s + bv;
    }
  }
}

extern "C" void kernel_launch(void* const* d_in, const int* in_sizes, int n_in,
                              void* d_out, int out_size, void* d_ws, size_t ws_size,
                              hipStream_t stream) {
  const float* x = (const float*)d_in[0];
  const int* qw = (const int*)d_in[1];  // harness pushes ints as int32
  const float* scale = (const float*)d_in[2];
  const float* bias = (const float*)d_in[3];
  float* out = (float*)d_out;

  const size_t wt_bytes = (size_t)N_DIM * K_DIM * 2;  // 8 MB
  const size_t xb_bytes = (size_t)M_DIM * K_DIM * 2;  // 64 MB
  bf16_t* wt = (bf16_t*)d_ws;
  bf16_t* xb = (bf16_t*)((char*)d_ws + wt_bytes);
  const bool apre = ws_size >= wt_bytes + xb_bytes;

  cvt_w_kernel<<<dim3((K_DIM / 64) * (N_DIM / 64)), dim3(256), 0, stream>>>(qw, wt);

  if (apre) {
    cvt_x_kernel<<<dim3(2048), dim3(256), 0, stream>>>(x, xb);
    gemm256_kernel<<<dim3((M_DIM / 256) * (N_DIM / 256)), dim3(512), 0, stream>>>(
        xb, wt, scale, bias, out);
  } else {
    gemm_fb_kernel<<<dim3((M_DIM / 128) * (N_DIM / 128)), dim3(256), 0, stream>>>(
        x, wt, scale, bias, out);
  }
}